// Round 1
// baseline (325.035 us; speedup 1.0000x reference)
//
#include <hip/hip_runtime.h>
#include <math.h>

// ALCOVE cell: B=256, D=64, H=2048, O=32
// RHO=2, TAU=1, BETA=6.5, GAMMA=0, PHI=2, LAM_A=0.001, LAM_W=0.003
//
// All work is batch-local -> single fused kernel, one block per batch row.
// Phases (per block b, 512 threads = 8 waves):
//   1. s[h]=exp(-beta*sqrt(S)), d[h]=sqrt(S) for all h  (wave-per-h, butterfly reduce)
//   2. x_out[o] = sum_h s[h]*assoc[b,h,o]  (float4-coalesced), teacher, g_x
//   3. new_assoc = assoc - lam_w*g_x[o]*s[h]; g_s[h]=sum_o g_x*assoc; coeff[h]=g_d/(2d)
//   4. g_att[d] = sum_h coeff[h]*(z[d]-c[h,d])^2 ; new_att = max(att - lam_a*g_att, 0)

#define BB 256
#define DD 64
#define HH 2048
#define OO 32
#define BETA 6.5f
#define PHI 2.0f
#define LAM_A 0.001f
#define LAM_W 0.003f

#define NT 512
#define NW (NT / 64)

__global__ __launch_bounds__(NT) void alcove_kernel(
    const float* __restrict__ z,
    const float* __restrict__ one_hot,
    const float* __restrict__ att,
    const float* __restrict__ assoc,
    const float* __restrict__ coords,
    float* __restrict__ out)
{
    __shared__ float s_arr[HH];
    __shared__ float d_arr[HH];
    __shared__ float coeff[HH];
    __shared__ float red[NT * 4];   // phase2: float4 partials; phase4: float partials (first NT)
    __shared__ float gx[OO];

    const int b = blockIdx.x;
    const int t = threadIdx.x;
    const int lane = t & 63;
    const int wave = t >> 6;

    // lane == d index for phases 1 & 4
    const float zd = z[b * DD + lane];
    const float pd = att[b * DD + lane];         // att[b,d]
    const float qd = pd * zd;                    // att*z

    // A = sum_d att*z^2 (full butterfly so every lane has it)
    float A = qd * zd;
    #pragma unroll
    for (int off = 1; off < 64; off <<= 1)
        A += __shfl_xor(A, off, 64);

    // ---- Phase 1: s[h], d[h] ----
    for (int h = wave; h < HH; h += NW) {
        float c = coords[h * DD + lane];
        // att*(z-c)^2 summed = A + sum_d c*(att*c - 2*att*z)
        float v = c * (pd * c - 2.0f * qd);
        #pragma unroll
        for (int off = 1; off < 64; off <<= 1)
            v += __shfl_xor(v, off, 64);
        if (lane == 0) {
            float S = A + v;
            S = S < 0.0f ? 0.0f : S;
            float dd = sqrtf(S);
            d_arr[h] = dd;
            s_arr[h] = expf(-BETA * dd);
        }
    }
    __syncthreads();

    // ---- Phase 2: x_out accumulation (float4 over o) ----
    const int o4 = t & 7;        // float4 column (o_base = o4*4)
    const int hloc = t >> 3;     // 0..63
    const float4* assoc4 = (const float4*)(assoc + (size_t)b * HH * OO);

    float4 acc = make_float4(0.f, 0.f, 0.f, 0.f);
    for (int chunk = 0; chunk < HH / 64; ++chunk) {
        int h = chunk * 64 + hloc;
        float sh = s_arr[h];
        float4 a = assoc4[h * (OO / 4) + o4];
        acc.x = fmaf(sh, a.x, acc.x);
        acc.y = fmaf(sh, a.y, acc.y);
        acc.z = fmaf(sh, a.z, acc.z);
        acc.w = fmaf(sh, a.w, acc.w);
    }
    ((float4*)red)[t] = acc;
    __syncthreads();

    if (t < OO) {
        const int base = t >> 2;   // o/4
        const int comp = t & 3;    // o%4
        float x = 0.0f;
        for (int g = 0; g < 64; ++g)
            x += red[(g * 8 + base) * 4 + comp];
        float oh = one_hot[b * OO + t];
        float tmin = fminf(-1.0f, x);
        float tmax = fmaxf(1.0f, x);
        float teacher = tmin - oh * tmin + oh * tmax;
        gx[t] = (2.0f / OO) * (x - teacher);
        out[b * OO + t] = PHI * x;              // output 0: x_out_scaled
    }
    __syncthreads();

    // ---- Phase 3: assoc update + g_s -> coeff[h] ----
    const float4 gxv = ((const float4*)gx)[o4];
    float4* out_assoc4 = (float4*)(out + BB * OO + BB * DD) + (size_t)b * HH * (OO / 4);
    for (int chunk = 0; chunk < HH / 64; ++chunk) {
        int h = chunk * 64 + hloc;
        float sh = s_arr[h];
        float4 a = assoc4[h * (OO / 4) + o4];
        float w = LAM_W * sh;
        float4 na;
        na.x = fmaf(-w, gxv.x, a.x);
        na.y = fmaf(-w, gxv.y, a.y);
        na.z = fmaf(-w, gxv.z, a.z);
        na.w = fmaf(-w, gxv.w, a.w);
        out_assoc4[h * (OO / 4) + o4] = na;     // output 2: new_association

        float part = a.x * gxv.x + a.y * gxv.y + a.z * gxv.z + a.w * gxv.w;
        part += __shfl_xor(part, 1, 64);
        part += __shfl_xor(part, 2, 64);
        part += __shfl_xor(part, 4, 64);        // all 8 lanes of the h-group have g_s
        if (o4 == 0) {
            float dd = d_arr[h];
            float g_d = -BETA * sh * part;
            coeff[h] = (dd > 0.0f) ? (g_d / (2.0f * dd)) : 0.0f;
        }
    }
    __syncthreads();

    // ---- Phase 4: attention gradient ----
    float accA = 0.0f;
    for (int h = wave; h < HH; h += NW) {
        float cf = coeff[h];
        float c = coords[h * DD + lane];
        float diff = zd - c;
        accA = fmaf(cf * diff, diff, accA);
    }
    red[t] = accA;
    __syncthreads();

    if (t < DD) {
        float g = 0.0f;
        #pragma unroll
        for (int gi = 0; gi < NW; ++gi)
            g += red[gi * 64 + t];
        float na = pd - LAM_A * g;              // pd == att[b,t] since lane==t here
        out[BB * OO + b * DD + t] = na > 0.0f ? na : 0.0f;   // output 1: new_attention
    }
}

extern "C" void kernel_launch(void* const* d_in, const int* in_sizes, int n_in,
                              void* d_out, int out_size, void* d_ws, size_t ws_size,
                              hipStream_t stream) {
    const float* z       = (const float*)d_in[0];
    const float* one_hot = (const float*)d_in[1];
    const float* att     = (const float*)d_in[2];
    const float* assoc   = (const float*)d_in[3];
    const float* coords  = (const float*)d_in[4];
    float* out = (float*)d_out;

    alcove_kernel<<<dim3(BB), dim3(NT), 0, stream>>>(z, one_hot, att, assoc, coords, out);
}

// Round 2
// 179.273 us; speedup vs baseline: 1.8131x; 1.8131x over previous
//
#include <hip/hip_runtime.h>
#include <math.h>

// ALCOVE cell: B=256, D=64, H=2048, O=32
// RHO=2, TAU=1, BETA=6.5, GAMMA=0, PHI=2, LAM_A=0.001, LAM_W=0.003
//
// R2: split H into 8 slices, 3 stream-ordered kernels for 8x more parallelism.
//   K1: per (b,slice): s,d (butterfly over d), partial x_out  -> ws
//   K2: per (b,slice): gx (recomputed from partials, cheap), assoc update,
//       g_s -> coeff, partial g_att -> ws; writes out0 + out2
//   K3: finalize new_attention (out1)
//
// ws layout (floats):
//   s_all      [B*H]        @ 0
//   d_all      [B*H]        @ B*H
//   px         [B*8*O]      @ 2*B*H
//   gatt_part  [B*8*D]      @ 2*B*H + B*8*O
// total = 2*524288 + 65536 + 131072 floats = 4.75 MB

#define BB 256
#define DD 64
#define HH 2048
#define OO 32
#define NSL 8
#define HS (HH / NSL)          // 256 h per slice
#define BETA 6.5f
#define PHI 2.0f
#define LAM_A 0.001f
#define LAM_W 0.003f
#define NT 256

__global__ __launch_bounds__(NT) void k1_sim(
    const float* __restrict__ z,
    const float* __restrict__ att,
    const float* __restrict__ assoc,
    const float* __restrict__ coords,
    float* __restrict__ s_all,
    float* __restrict__ d_all,
    float* __restrict__ px)
{
    __shared__ float s_loc[HS];
    __shared__ float red[NT * 4];

    const int b  = blockIdx.x >> 3;
    const int sl = blockIdx.x & 7;
    const int base = sl * HS;
    const int t = threadIdx.x;
    const int lane = t & 63;
    const int wave = t >> 6;       // 0..3

    const float zd = z[b * DD + lane];
    const float pd = att[b * DD + lane];
    const float qd = pd * zd;

    float A = qd * zd;
    #pragma unroll
    for (int off = 1; off < 64; off <<= 1)
        A += __shfl_xor(A, off, 64);

    // ---- s,d for this slice: each wave a contiguous 64-h chunk ----
    for (int i = 0; i < 64; ++i) {
        int hl = wave * 64 + i;
        int h = base + hl;
        float c = coords[h * DD + lane];
        float v = c * (pd * c - 2.0f * qd);
        #pragma unroll
        for (int off = 1; off < 64; off <<= 1)
            v += __shfl_xor(v, off, 64);
        if (lane == 0) {
            float S = A + v;
            S = S < 0.0f ? 0.0f : S;
            float dd = sqrtf(S);
            float sh = expf(-BETA * dd);
            d_all[b * HH + h] = dd;
            s_all[b * HH + h] = sh;
            s_loc[hl] = sh;
        }
    }
    __syncthreads();

    // ---- partial x_out over this slice ----
    const int o4 = t & 7;       // float4 column
    const int hl = t >> 3;      // 0..31
    const float4* assoc4 = (const float4*)(assoc + (size_t)b * HH * OO);

    float4 acc = make_float4(0.f, 0.f, 0.f, 0.f);
    #pragma unroll
    for (int chunk = 0; chunk < HS / 32; ++chunk) {
        int hloc = chunk * 32 + hl;
        float sh = s_loc[hloc];
        float4 a = assoc4[(base + hloc) * (OO / 4) + o4];
        acc.x = fmaf(sh, a.x, acc.x);
        acc.y = fmaf(sh, a.y, acc.y);
        acc.z = fmaf(sh, a.z, acc.z);
        acc.w = fmaf(sh, a.w, acc.w);
    }
    ((float4*)red)[t] = acc;
    __syncthreads();

    if (t < OO) {
        const int b4 = t >> 2, comp = t & 3;
        float x = 0.0f;
        #pragma unroll 8
        for (int g = 0; g < 32; ++g)
            x += red[(g * 8 + b4) * 4 + comp];
        px[(b * NSL + sl) * OO + t] = x;
    }
}

__global__ __launch_bounds__(NT) void k2_upd(
    const float* __restrict__ z,
    const float* __restrict__ one_hot,
    const float* __restrict__ assoc,
    const float* __restrict__ coords,
    const float* __restrict__ s_all,
    const float* __restrict__ d_all,
    const float* __restrict__ px,
    float* __restrict__ gatt_part,
    float* __restrict__ out)
{
    __shared__ float gx_s[OO];
    __shared__ float s_loc[HS];
    __shared__ float d_loc[HS];
    __shared__ float coeff[HS];
    __shared__ float red[NT];

    const int b  = blockIdx.x >> 3;
    const int sl = blockIdx.x & 7;
    const int base = sl * HS;
    const int t = threadIdx.x;
    const int lane = t & 63;
    const int wave = t >> 6;

    // gx (each block recomputes for its b — 8 partial reads, cheap)
    if (t < OO) {
        float x = 0.0f;
        #pragma unroll
        for (int s2 = 0; s2 < NSL; ++s2)
            x += px[(b * NSL + s2) * OO + t];
        float oh = one_hot[b * OO + t];
        float tmin = fminf(-1.0f, x);
        float tmax = fmaxf(1.0f, x);
        float teacher = tmin - oh * tmin + oh * tmax;
        gx_s[t] = (2.0f / OO) * (x - teacher);
        if (sl == 0)
            out[b * OO + t] = PHI * x;                   // output 0
    }
    // stage s,d slice
    s_loc[t] = s_all[b * HH + base + t];
    d_loc[t] = d_all[b * HH + base + t];
    __syncthreads();

    // ---- assoc update + g_s -> coeff ----
    const int o4 = t & 7;
    const int hl = t >> 3;
    const float4 gxv = ((const float4*)gx_s)[o4];
    const float4* assoc4 = (const float4*)(assoc + (size_t)b * HH * OO);
    float4* out_assoc4 = (float4*)(out + BB * OO + BB * DD) + (size_t)b * HH * (OO / 4);

    #pragma unroll
    for (int chunk = 0; chunk < HS / 32; ++chunk) {
        int hloc = chunk * 32 + hl;
        float sh = s_loc[hloc];
        float4 a = assoc4[(base + hloc) * (OO / 4) + o4];
        float w = LAM_W * sh;
        float4 na;
        na.x = fmaf(-w, gxv.x, a.x);
        na.y = fmaf(-w, gxv.y, a.y);
        na.z = fmaf(-w, gxv.z, a.z);
        na.w = fmaf(-w, gxv.w, a.w);
        out_assoc4[(base + hloc) * (OO / 4) + o4] = na;  // output 2

        float part = a.x * gxv.x + a.y * gxv.y + a.z * gxv.z + a.w * gxv.w;
        part += __shfl_xor(part, 1, 64);
        part += __shfl_xor(part, 2, 64);
        part += __shfl_xor(part, 4, 64);
        if (o4 == 0) {
            float dd = d_loc[hloc];
            float g_d = -BETA * sh * part;
            coeff[hloc] = (dd > 0.0f) ? (g_d / (2.0f * dd)) : 0.0f;
        }
    }
    __syncthreads();

    // ---- partial g_att over this slice (lane == d) ----
    const float zd = z[b * DD + lane];
    float acc = 0.0f;
    for (int i = 0; i < 64; ++i) {
        int hloc = wave * 64 + i;
        float cf = coeff[hloc];
        float c = coords[(base + hloc) * DD + lane];
        float diff = zd - c;
        acc = fmaf(cf * diff, diff, acc);
    }
    red[t] = acc;
    __syncthreads();

    if (t < DD) {
        float g = red[t] + red[64 + t] + red[128 + t] + red[192 + t];
        gatt_part[(b * NSL + sl) * DD + t] = g;
    }
}

__global__ __launch_bounds__(NT) void k3_att(
    const float* __restrict__ att,
    const float* __restrict__ gatt_part,
    float* __restrict__ out)
{
    int idx = blockIdx.x * NT + threadIdx.x;   // 0 .. B*D-1
    int b = idx >> 6;
    int d = idx & 63;
    float g = 0.0f;
    #pragma unroll
    for (int sl = 0; sl < NSL; ++sl)
        g += gatt_part[(b * NSL + sl) * DD + d];
    float na = att[b * DD + d] - LAM_A * g;
    out[BB * OO + idx] = na > 0.0f ? na : 0.0f;          // output 1
}

extern "C" void kernel_launch(void* const* d_in, const int* in_sizes, int n_in,
                              void* d_out, int out_size, void* d_ws, size_t ws_size,
                              hipStream_t stream) {
    const float* z       = (const float*)d_in[0];
    const float* one_hot = (const float*)d_in[1];
    const float* att     = (const float*)d_in[2];
    const float* assoc   = (const float*)d_in[3];
    const float* coords  = (const float*)d_in[4];
    float* out = (float*)d_out;

    float* ws = (float*)d_ws;
    float* s_all     = ws;                            // B*H
    float* d_all     = s_all + BB * HH;               // B*H
    float* px        = d_all + BB * HH;               // B*8*O
    float* gatt_part = px + BB * NSL * OO;            // B*8*D

    k1_sim<<<dim3(BB * NSL), dim3(NT), 0, stream>>>(z, att, assoc, coords,
                                                    s_all, d_all, px);
    k2_upd<<<dim3(BB * NSL), dim3(NT), 0, stream>>>(z, one_hot, assoc, coords,
                                                    s_all, d_all, px, gatt_part, out);
    k3_att<<<dim3((BB * DD) / NT), dim3(NT), 0, stream>>>(att, gatt_part, out);
}

// Round 3
// 143.188 us; speedup vs baseline: 2.2700x; 1.2520x over previous
//
#include <hip/hip_runtime.h>
#include <math.h>

// ALCOVE cell: B=256, D=64, H=2048, O=32
// RHO=2, TAU=1, BETA=6.5, GAMMA=0, PHI=2, LAM_A=0.001, LAM_W=0.003
//
// R3: eliminate butterfly-shuffle latency chains in K1 (the R2 hotspot).
//   K0: transpose coords -> ct[d][h]  (one-shot, 512 KB, L2-resident)
//   K1: thread-per-(b,h): S = sum_d att_d*(z_d-ct[d][h])^2 via coalesced
//       ct loads + LDS float2 broadcast; s=exp(-beta*sqrt(S));
//       r = -beta*s/(2d); partial x_out -> ws.  NO cross-lane ops.
//   K2: gx from partials, assoc update + g_s -> coeff = r*g_s,
//       partial g_att -> ws; writes out0 + out2
//   K3: finalize new_attention (out1)
//
// ws layout (floats):
//   ct         [D*H]     = 131072
//   s_all      [B*H]     = 524288
//   r_all      [B*H]     = 524288
//   px         [B*8*O]   = 65536
//   gatt_part  [B*8*D]   = 131072     total 5.25 MB

#define BB 256
#define DD 64
#define HH 2048
#define OO 32
#define NSL 8
#define HS (HH / NSL)          // 256 h per slice/block
#define BETA 6.5f
#define PHI 2.0f
#define LAM_A 0.001f
#define LAM_W 0.003f
#define NT 256

__global__ __launch_bounds__(NT) void k0_transpose(
    const float* __restrict__ coords, float* __restrict__ ct)
{
    int idx = blockIdx.x * NT + threadIdx.x;   // 0 .. D*H-1, ct-linear
    int d = idx >> 11;                         // / HH
    int h = idx & (HH - 1);
    ct[idx] = coords[h * DD + d];
}

__global__ __launch_bounds__(NT) void k1_sim(
    const float* __restrict__ z,
    const float* __restrict__ att,
    const float* __restrict__ assoc,
    const float* __restrict__ ct,
    float* __restrict__ s_all,
    float* __restrict__ r_all,
    float* __restrict__ px)
{
    __shared__ float2 za[DD];      // (z_d, att_d)
    __shared__ float s_loc[HS];
    __shared__ float red[NT * 4];

    const int b  = blockIdx.x >> 3;
    const int sl = blockIdx.x & 7;
    const int base = sl * HS;
    const int t = threadIdx.x;
    const int h = base + t;        // thread-per-h

    if (t < DD)
        za[t] = make_float2(z[b * DD + t], att[b * DD + t]);
    __syncthreads();

    // ---- distance/similarity: coalesced ct column reads, no shuffles ----
    float S = 0.0f;
    const float* ctp = ct + h;
    #pragma unroll 8
    for (int d = 0; d < DD; ++d) {
        float2 p = za[d];                  // broadcast ds_read_b64
        float c = ctp[d * HH];             // coalesced across threads
        float diff = p.x - c;
        S = fmaf(p.y * diff, diff, S);
    }
    S = S < 0.0f ? 0.0f : S;
    float dd = sqrtf(S);
    float sh = expf(-BETA * dd);
    s_all[b * HH + h] = sh;
    r_all[b * HH + h] = (dd > 0.0f) ? (-BETA * sh / (2.0f * dd)) : 0.0f;
    s_loc[t] = sh;
    __syncthreads();

    // ---- partial x_out over this slice (float4 over o) ----
    const int o4 = t & 7;       // float4 column
    const int hl = t >> 3;      // 0..31
    const float4* assoc4 = (const float4*)(assoc + (size_t)b * HH * OO);

    float4 acc = make_float4(0.f, 0.f, 0.f, 0.f);
    #pragma unroll
    for (int chunk = 0; chunk < HS / 32; ++chunk) {
        int hloc = chunk * 32 + hl;
        float s2 = s_loc[hloc];
        float4 a = assoc4[(base + hloc) * (OO / 4) + o4];
        acc.x = fmaf(s2, a.x, acc.x);
        acc.y = fmaf(s2, a.y, acc.y);
        acc.z = fmaf(s2, a.z, acc.z);
        acc.w = fmaf(s2, a.w, acc.w);
    }
    ((float4*)red)[t] = acc;
    __syncthreads();

    if (t < OO) {
        const int b4 = t >> 2, comp = t & 3;
        float x = 0.0f;
        #pragma unroll 8
        for (int g = 0; g < 32; ++g)
            x += red[(g * 8 + b4) * 4 + comp];
        px[(b * NSL + sl) * OO + t] = x;
    }
}

__global__ __launch_bounds__(NT) void k2_upd(
    const float* __restrict__ z,
    const float* __restrict__ one_hot,
    const float* __restrict__ assoc,
    const float* __restrict__ coords,
    const float* __restrict__ s_all,
    const float* __restrict__ r_all,
    const float* __restrict__ px,
    float* __restrict__ gatt_part,
    float* __restrict__ out)
{
    __shared__ float gx_s[OO];
    __shared__ float s_loc[HS];
    __shared__ float r_loc[HS];
    __shared__ float coeff[HS];
    __shared__ float red[NT];

    const int b  = blockIdx.x >> 3;
    const int sl = blockIdx.x & 7;
    const int base = sl * HS;
    const int t = threadIdx.x;
    const int lane = t & 63;
    const int wave = t >> 6;

    if (t < OO) {
        float x = 0.0f;
        #pragma unroll
        for (int s2 = 0; s2 < NSL; ++s2)
            x += px[(b * NSL + s2) * OO + t];
        float oh = one_hot[b * OO + t];
        float tmin = fminf(-1.0f, x);
        float tmax = fmaxf(1.0f, x);
        float teacher = tmin - oh * tmin + oh * tmax;
        gx_s[t] = (2.0f / OO) * (x - teacher);
        if (sl == 0)
            out[b * OO + t] = PHI * x;                   // output 0
    }
    s_loc[t] = s_all[b * HH + base + t];
    r_loc[t] = r_all[b * HH + base + t];
    __syncthreads();

    // ---- assoc update + g_s -> coeff ----
    const int o4 = t & 7;
    const int hl = t >> 3;
    const float4 gxv = ((const float4*)gx_s)[o4];
    const float4* assoc4 = (const float4*)(assoc + (size_t)b * HH * OO);
    float4* out_assoc4 = (float4*)(out + BB * OO + BB * DD) + (size_t)b * HH * (OO / 4);

    #pragma unroll
    for (int chunk = 0; chunk < HS / 32; ++chunk) {
        int hloc = chunk * 32 + hl;
        float sh = s_loc[hloc];
        float4 a = assoc4[(base + hloc) * (OO / 4) + o4];
        float w = LAM_W * sh;
        float4 na;
        na.x = fmaf(-w, gxv.x, a.x);
        na.y = fmaf(-w, gxv.y, a.y);
        na.z = fmaf(-w, gxv.z, a.z);
        na.w = fmaf(-w, gxv.w, a.w);
        out_assoc4[(base + hloc) * (OO / 4) + o4] = na;  // output 2

        float part = a.x * gxv.x + a.y * gxv.y + a.z * gxv.z + a.w * gxv.w;
        part += __shfl_xor(part, 1, 64);
        part += __shfl_xor(part, 2, 64);
        part += __shfl_xor(part, 4, 64);
        if (o4 == 0)
            coeff[hloc] = r_loc[hloc] * part;   // g_d/(2d) = -beta*s*g_s/(2d)
    }
    __syncthreads();

    // ---- partial g_att over this slice (lane == d) ----
    const float zd = z[b * DD + lane];
    float acc = 0.0f;
    #pragma unroll 4
    for (int i = 0; i < 64; ++i) {
        int hloc = wave * 64 + i;
        float cf = coeff[hloc];
        float c = coords[(base + hloc) * DD + lane];
        float diff = zd - c;
        acc = fmaf(cf * diff, diff, acc);
    }
    red[t] = acc;
    __syncthreads();

    if (t < DD) {
        float g = red[t] + red[64 + t] + red[128 + t] + red[192 + t];
        gatt_part[(b * NSL + sl) * DD + t] = g;
    }
}

__global__ __launch_bounds__(NT) void k3_att(
    const float* __restrict__ att,
    const float* __restrict__ gatt_part,
    float* __restrict__ out)
{
    int idx = blockIdx.x * NT + threadIdx.x;   // 0 .. B*D-1
    int b = idx >> 6;
    int d = idx & 63;
    float g = 0.0f;
    #pragma unroll
    for (int sl = 0; sl < NSL; ++sl)
        g += gatt_part[(b * NSL + sl) * DD + d];
    float na = att[b * DD + d] - LAM_A * g;
    out[BB * OO + idx] = na > 0.0f ? na : 0.0f;          // output 1
}

extern "C" void kernel_launch(void* const* d_in, const int* in_sizes, int n_in,
                              void* d_out, int out_size, void* d_ws, size_t ws_size,
                              hipStream_t stream) {
    const float* z       = (const float*)d_in[0];
    const float* one_hot = (const float*)d_in[1];
    const float* att     = (const float*)d_in[2];
    const float* assoc   = (const float*)d_in[3];
    const float* coords  = (const float*)d_in[4];
    float* out = (float*)d_out;

    float* ws = (float*)d_ws;
    float* ct        = ws;                            // D*H
    float* s_all     = ct + DD * HH;                  // B*H
    float* r_all     = s_all + BB * HH;               // B*H
    float* px        = r_all + BB * HH;               // B*8*O
    float* gatt_part = px + BB * NSL * OO;            // B*8*D

    k0_transpose<<<dim3((DD * HH) / NT), dim3(NT), 0, stream>>>(coords, ct);
    k1_sim<<<dim3(BB * NSL), dim3(NT), 0, stream>>>(z, att, assoc, ct,
                                                    s_all, r_all, px);
    k2_upd<<<dim3(BB * NSL), dim3(NT), 0, stream>>>(z, one_hot, assoc, coords,
                                                    s_all, r_all, px, gatt_part, out);
    k3_att<<<dim3((BB * DD) / NT), dim3(NT), 0, stream>>>(att, gatt_part, out);
}